// Round 10
// baseline (1117.895 us; speedup 1.0000x reference)
//
#include <hip/hip_runtime.h>
#include <math.h>

// ---------------------------------------------------------------------------
// NoPropDTEncoder forward, round 10:
//  - cs_kernel rewrite: wave-per-(t,i), lane-split coalesced dot over n,
//    all 16 modes per wave (proj_w read once; was 64-line/instr scatter)
//  - attn: 3-stage named-buffer register pipeline (issue-to-use = 2 compute
//    bodies ~500cyc) to cover HBM latency; math identical to round 9
//  - rest identical to round 9
// ---------------------------------------------------------------------------

#define DEV __device__ __forceinline__

typedef unsigned int   uint32;
typedef unsigned short ushort_t;
typedef __attribute__((ext_vector_type(8))) short bf16x8;
typedef __attribute__((ext_vector_type(4))) float f32x4;
typedef __attribute__((ext_vector_type(2))) float f32x2;

constexpr int Bv  = 256;
constexpr int Sv  = 512;
constexpr int Dv  = 768;
constexpr int Hv  = 8;
constexpr int DHv = 96;
constexpr int NCv = 14;

constexpr size_t ZL  = 196608;     // lo-plane offset for z/q/o (B*D)
constexpr size_t XWL = 1572864;    // lo-plane offset for xw (B*H*D)
constexpr size_t WL  = 2359296;    // lo-plane offset for weights (4*768*768)
constexpr size_t WT  = 589824;     // per-t weight slice (768*768)

DEV float4 ld4(const float* p) { return *reinterpret_cast<const float4*>(p); }

DEV ushort_t f2bf(float f) {
    uint32 u = __float_as_uint(f);
    u += 0x7FFFu + ((u >> 16) & 1u);
    return (ushort_t)(u >> 16);
}
DEV float bf2f(ushort_t h) { return __uint_as_float((uint32)h << 16); }
DEV void split2(float f, ushort_t& hi, ushort_t& lo) {
    hi = f2bf(f);
    lo = f2bf(f - bf2f(hi));
}
DEV uint2 pack4(float4 v) {
    return make_uint2((uint32)f2bf(v.x) | ((uint32)f2bf(v.y) << 16),
                      (uint32)f2bf(v.z) | ((uint32)f2bf(v.w) << 16));
}

// unpack a bf16 pair (packed in uint32) to f32x2
DEV f32x2 bfpair(uint32 u) {
    f32x2 r;
    r.x = __uint_as_float(u << 16);
    r.y = __uint_as_float(u & 0xFFFF0000u);
    return r;
}

// packed fp32 FMA (gfx90a+ v_pk_fma_f32): d = a*b + c on both halves
DEV f32x2 pkfma(f32x2 a, f32x2 b, f32x2 c) {
    f32x2 d;
    asm("v_pk_fma_f32 %0, %1, %2, %3" : "=v"(d) : "v"(a), "v"(b), "v"(c));
    return d;
}

DEV void glds16(const void* g, void* l) {
    __builtin_amdgcn_global_load_lds(
        (const __attribute__((address_space(1))) void*)g,
        (__attribute__((address_space(3))) void*)l, 16, 0, 0);
}

// ---------------------------------------------------------------------------
// Pooling + x->bf16 conversion. grid (B, 2). Partials -> ws (NP=16, NH=1).
// ---------------------------------------------------------------------------
__global__ __launch_bounds__(512, 4)
void pool_cvt_kernel(const float* __restrict__ x, const float* __restrict__ pool_w,
                     ushort_t* __restrict__ xbf,
                     float* __restrict__ pacc, float2* __restrict__ pml)
{
    __shared__ float qks[Dv];
    const int b = blockIdx.x, half = blockIdx.y;
    const int tid = threadIdx.x, wave = tid >> 6, lane = tid & 63;
    for (int i = tid; i < Dv / 4; i += 512)
        *reinterpret_cast<float4*>(&qks[i * 4]) = ld4(pool_w + i * 4);
    __syncthreads();

    const int row0 = half * 256 + wave * 32;
    const float* base = x + ((size_t)b * Sv + row0) * Dv + 4 * lane;

    float4 acc[3];
#pragma unroll
    for (int j = 0; j < 3; ++j) acc[j] = make_float4(0.f, 0.f, 0.f, 0.f);
    float m = -INFINITY, l = 0.f;

    float4 c0[3], c1[3];
#pragma unroll
    for (int j = 0; j < 3; ++j) { c0[j] = ld4(base + 256 * j); c1[j] = ld4(base + Dv + 256 * j); }

    for (int it = 0; it < 16; ++it) {
        float4 n0_[3], n1_[3];
        if (it < 15) {
            const float* nb = base + (size_t)(2 * it + 2) * Dv;
#pragma unroll
            for (int j = 0; j < 3; ++j) { n0_[j] = ld4(nb + 256 * j); n1_[j] = ld4(nb + Dv + 256 * j); }
        }
        ushort_t* ob = xbf + ((size_t)b * Sv + row0 + 2 * it) * Dv + 4 * lane;
#pragma unroll
        for (int j = 0; j < 3; ++j) *reinterpret_cast<uint2*>(ob + 256 * j) = pack4(c0[j]);
#pragma unroll
        for (int j = 0; j < 3; ++j) *reinterpret_cast<uint2*>(ob + Dv + 256 * j) = pack4(c1[j]);
        float p0 = 0.f, p1 = 0.f;
#pragma unroll
        for (int j = 0; j < 3; ++j) {
            const float4 q4 = *reinterpret_cast<const float4*>(&qks[4 * lane + 256 * j]);
            p0 = fmaf(q4.x, c0[j].x, p0); p0 = fmaf(q4.y, c0[j].y, p0);
            p0 = fmaf(q4.z, c0[j].z, p0); p0 = fmaf(q4.w, c0[j].w, p0);
            p1 = fmaf(q4.x, c1[j].x, p1); p1 = fmaf(q4.y, c1[j].y, p1);
            p1 = fmaf(q4.z, c1[j].z, p1); p1 = fmaf(q4.w, c1[j].w, p1);
        }
#pragma unroll
        for (int dd = 1; dd < 64; dd <<= 1) { p0 += __shfl_xor(p0, dd); p1 += __shfl_xor(p1, dd); }
        float mx = fmaxf(p0, p1);
        if (mx > m) {
            float r = __expf(m - mx); l *= r;
#pragma unroll
            for (int j = 0; j < 3; ++j) { acc[j].x *= r; acc[j].y *= r; acc[j].z *= r; acc[j].w *= r; }
            m = mx;
        }
        float w0 = __expf(p0 - m), w1 = __expf(p1 - m);
        l += w0 + w1;
#pragma unroll
        for (int j = 0; j < 3; ++j) {
            acc[j].x = fmaf(w1, c1[j].x, fmaf(w0, c0[j].x, acc[j].x));
            acc[j].y = fmaf(w1, c1[j].y, fmaf(w0, c0[j].y, acc[j].y));
            acc[j].z = fmaf(w1, c1[j].z, fmaf(w0, c0[j].z, acc[j].z));
            acc[j].w = fmaf(w1, c1[j].w, fmaf(w0, c0[j].w, acc[j].w));
        }
        if (it < 15) {
#pragma unroll
            for (int j = 0; j < 3; ++j) { c0[j] = n0_[j]; c1[j] = n1_[j]; }
        }
    }
    const int p = half * 8 + wave;
    const size_t pidx = (size_t)p * 256 + b;
#pragma unroll
    for (int j = 0; j < 3; ++j)
        *reinterpret_cast<float4*>(&pacc[pidx * Dv + 4 * lane + 256 * j]) = acc[j];
    if (lane == 0) pml[pidx] = make_float2(m, l);
}

// ---------------------------------------------------------------------------
// Attention streaming pass (bf16 x). grid (B, 2). Wave w: heads {2(w&3),
// 2(w&3)+1}, rows [half*256 + (w>>2)*128, +128). No LDS, no barriers;
// 3-stage named-buffer register pipeline (X/Y/Z), pk_fma, fold-4 reduce.
// Partials NP=4 (p = half*2 + slice).
// ---------------------------------------------------------------------------
__global__ __launch_bounds__(512, 4)
void attn_flash_kernel(const ushort_t* __restrict__ xbf, const float* __restrict__ Qk,
                       float* __restrict__ pacc, float2* __restrict__ pml, float scale)
{
    const int b = blockIdx.x, half = blockIdx.y;
    const int tid = threadIdx.x, wave = tid >> 6, lane = tid & 63;
    const int hg = wave & 3, slice = wave >> 2;
    const int h0 = 2 * hg, h1 = h0 + 1;
    const int row0 = half * 256 + slice * 128;

    // q for both heads: 6 f32x2 pairs each, cols {seg*256+4l .. +4}
    f32x2 q0[6], q1[6];
    {
        const float* qp0 = Qk + ((size_t)b * Hv + h0) * Dv + 4 * lane;
        const float* qp1 = Qk + ((size_t)b * Hv + h1) * Dv + 4 * lane;
#pragma unroll
        for (int s = 0; s < 3; ++s) {
            float4 a = ld4(qp0 + s * 256);
            float4 c = ld4(qp1 + s * 256);
            q0[2 * s]     = (f32x2){a.x, a.y}; q0[2 * s + 1] = (f32x2){a.z, a.w};
            q1[2 * s]     = (f32x2){c.x, c.y}; q1[2 * s + 1] = (f32x2){c.z, c.w};
        }
    }
    f32x2 a0[6], a1[6];
#pragma unroll
    for (int c = 0; c < 6; ++c) { a0[c] = (f32x2){0.f, 0.f}; a1[c] = (f32x2){0.f, 0.f}; }
    float m0 = -INFINITY, l0 = 0.f, m1 = -INFINITY, l1 = 0.f;

    const ushort_t* base = xbf + ((size_t)b * Sv + row0) * Dv + 4 * lane;

    // buffer layout: B[0..2] = row 2it segs, B[3..5] = row 2it+1 segs
    uint2 X[6], Y[6], Z[6];

    auto loadbuf = [&](uint2* B, int it) {
        const ushort_t* nb = base + (size_t)(2 * it) * Dv;
#pragma unroll
        for (int s = 0; s < 3; ++s) {
            B[s]     = *reinterpret_cast<const uint2*>(nb + s * 256);
            B[3 + s] = *reinterpret_cast<const uint2*>(nb + Dv + s * 256);
        }
    };

    auto compute = [&](const uint2* B) {
        // unpack both rows
        f32x2 xf0[6], xf1[6];
#pragma unroll
        for (int s = 0; s < 3; ++s) {
            xf0[2 * s] = bfpair(B[s].x);     xf0[2 * s + 1] = bfpair(B[s].y);
            xf1[2 * s] = bfpair(B[3 + s].x); xf1[2 * s + 1] = bfpair(B[3 + s].y);
        }
        // scores: 2 rows x 2 heads
        f32x2 t00 = (f32x2){0.f, 0.f}, t01 = t00, t10 = t00, t11 = t00;
#pragma unroll
        for (int c = 0; c < 6; ++c) {
            t00 = pkfma(xf0[c], q0[c], t00);
            t01 = pkfma(xf0[c], q1[c], t01);
            t10 = pkfma(xf1[c], q0[c], t10);
            t11 = pkfma(xf1[c], q1[c], t11);
        }
        float s4[4];
        s4[0] = t00.x + t00.y;   // row0, h0
        s4[1] = t01.x + t01.y;   // row0, h1
        s4[2] = t10.x + t10.y;   // row1, h0
        s4[3] = t11.x + t11.y;   // row1, h1
        // ---- folded reduce: 4 values over 64 lanes, broadcast ----
        {
            const bool k0 = (lane & 1), k1 = (lane & 2);
            float sd0 = k0 ? s4[0] : s4[1];
            float rc0 = __shfl_xor(sd0, 1);
            float t0  = (k0 ? s4[1] : s4[0]) + rc0;
            float sd1 = k0 ? s4[2] : s4[3];
            float rc1 = __shfl_xor(sd1, 1);
            float t1  = (k0 ? s4[3] : s4[2]) + rc1;
            float sd2 = k1 ? t0 : t1;
            float rc2 = __shfl_xor(sd2, 2);
            float u   = (k1 ? t1 : t0) + rc2;
            u += __shfl_xor(u, 4);  u += __shfl_xor(u, 8);
            u += __shfl_xor(u, 16); u += __shfl_xor(u, 32);
            float b1 = __shfl_xor(u, 1);
            float b2 = __shfl_xor(u, 2);
            float b3 = __shfl_xor(u, 3);
            s4[0] = k1 ? (k0 ? b3 : b2) : (k0 ? b1 : u);
            s4[1] = k1 ? (k0 ? b2 : b3) : (k0 ? u  : b1);
            s4[2] = k1 ? (k0 ? b1 : u ) : (k0 ? b3 : b2);
            s4[3] = k1 ? (k0 ? u  : b1) : (k0 ? b2 : b3);
        }
#pragma unroll
        for (int j = 0; j < 4; ++j) s4[j] *= scale;
        // head 0 (rows: s4[0], s4[2])
        {
            float mx = fmaxf(s4[0], s4[2]);
            if (mx > m0) {
                float f = __expf(m0 - mx); l0 *= f;
#pragma unroll
                for (int c = 0; c < 6; ++c) { a0[c].x *= f; a0[c].y *= f; }
                m0 = mx;
            }
            float w0 = __expf(s4[0] - m0), w1 = __expf(s4[2] - m0);
            l0 += w0 + w1;
            f32x2 w02 = (f32x2){w0, w0}, w12 = (f32x2){w1, w1};
#pragma unroll
            for (int c = 0; c < 6; ++c) a0[c] = pkfma(xf1[c], w12, pkfma(xf0[c], w02, a0[c]));
        }
        // head 1 (rows: s4[1], s4[3])
        {
            float mx = fmaxf(s4[1], s4[3]);
            if (mx > m1) {
                float f = __expf(m1 - mx); l1 *= f;
#pragma unroll
                for (int c = 0; c < 6; ++c) { a1[c].x *= f; a1[c].y *= f; }
                m1 = mx;
            }
            float w0 = __expf(s4[1] - m1), w1 = __expf(s4[3] - m1);
            l1 += w0 + w1;
            f32x2 w02 = (f32x2){w0, w0}, w12 = (f32x2){w1, w1};
#pragma unroll
            for (int c = 0; c < 6; ++c) a1[c] = pkfma(xf1[c], w12, pkfma(xf0[c], w02, a1[c]));
        }
    };

    // 3-stage rotating pipeline: 64 iterations (2 rows each)
    loadbuf(X, 0);
    loadbuf(Y, 1);
    for (int k = 0; k < 21; ++k) {
        loadbuf(Z, 3 * k + 2);
        compute(X);
        loadbuf(X, 3 * k + 3);          // k=20 -> it 63 (last)
        compute(Y);
        if (3 * k + 4 < 64) loadbuf(Y, 3 * k + 4);
        compute(Z);
    }
    compute(X);                          // it = 63

    const int p = half * 2 + slice;
    const size_t pidx0 = ((size_t)p * 256 + b) * Hv + h0;
    const size_t pidx1 = pidx0 + 1;
    float* pb0 = pacc + pidx0 * Dv + 4 * lane;
    float* pb1 = pacc + pidx1 * Dv + 4 * lane;
#pragma unroll
    for (int s = 0; s < 3; ++s) {
        *reinterpret_cast<float4*>(pb0 + s * 256) =
            make_float4(a0[2 * s].x, a0[2 * s].y, a0[2 * s + 1].x, a0[2 * s + 1].y);
        *reinterpret_cast<float4*>(pb1 + s * 256) =
            make_float4(a1[2 * s].x, a1[2 * s].y, a1[2 * s + 1].x, a1[2 * s + 1].y);
    }
    if (lane == 0) {
        pml[pidx0] = make_float2(m0, l0);
        pml[pidx1] = make_float2(m1, l1);
    }
}

// ---------------------------------------------------------------------------
// Merge NP partials -> split bf16 (hi at obf, lo at obf+loOff), opt f32.
// ---------------------------------------------------------------------------
template<int NH, int NP, bool WF32>
__global__ __launch_bounds__(256)
void merge_kernel(const float* __restrict__ pacc, const float2* __restrict__ pml,
                  ushort_t* __restrict__ obf, size_t loOff, float* __restrict__ of32)
{
    __shared__ float eS[NH * NP];
    const int b = blockIdx.x, tid = threadIdx.x;
    if (tid < NH) {
        float2 mls[NP];
        float mm = -INFINITY;
#pragma unroll
        for (int p = 0; p < NP; ++p) {
            mls[p] = pml[((size_t)p * 256 + b) * NH + tid];
            mm = fmaxf(mm, mls[p].x);
        }
        float ee[NP]; float L = 0.f;
#pragma unroll
        for (int p = 0; p < NP; ++p) { ee[p] = __expf(mls[p].x - mm); L += mls[p].y * ee[p]; }
        float inv = 1.f / L;
#pragma unroll
        for (int p = 0; p < NP; ++p) eS[tid * NP + p] = ee[p] * inv;
    }
    __syncthreads();
#pragma unroll
    for (int seg = 0; seg < NH * 3; ++seg) {
        int h = seg / 3;
        int d = (seg - h * 3) * 256 + tid;
        float v = 0.f;
#pragma unroll
        for (int p = 0; p < NP; ++p)
            v += pacc[((size_t)((size_t)p * 256 + b) * NH + h) * Dv + d] * eS[h * NP + p];
        size_t oi = ((size_t)b * NH + h) * Dv + d;
        ushort_t hi, lo; split2(v, hi, lo);
        obf[oi] = hi; obf[oi + loOff] = lo;
        if (WF32) of32[oi] = v;
    }
}

// ---------------------------------------------------------------------------
// SPLIT-bf16 MFMA GEMM: out[m,n] = bias[n] + sum_k A[m,k]*W[n,k], A,W as
// hi/lo pairs. MODE 0: BN=64 BK=64 K=768; MODE 1: BN=64 BK=32 K=96
// grid.z=head; MODE 2: BN=96 BK=64 K=768, h=n0/96, A col offset h*768.
// ---------------------------------------------------------------------------
template<int MODE, bool OBF>
__global__ __launch_bounds__(256)
void mgemm_kernel(const ushort_t* __restrict__ A, size_t aLo,
                  const ushort_t* __restrict__ W, size_t wLo,
                  const float* __restrict__ bias, void* __restrict__ outp,
                  size_t oLo)
{
    constexpr int BN = (MODE == 2) ? 96 : 64;
    constexpr int BK = (MODE == 1) ? 32 : 64;
    constexpr int NJ = BN / 32;
    constexpr int KTOT = (MODE == 1) ? 96 : 768;
    constexpr int NSTEP = KTOT / BK;
    constexpr int CH = BK / 8;
    constexpr int CA = (64 * BK) / 512;
    constexpr int CB = (BN * BK) / 512;
    constexpr int NC = 2 * (CA + CB) / 4;    // per-wave glds calls per stage
    constexpr int LDA = (MODE == 2) ? 6144 : 768;
    constexpr int LDW = (MODE == 1) ? 96 : 768;
    constexpr int LDO = (MODE == 1) ? 6144 : 768;
    constexpr int WCW = (MODE == 2) ? 48 : 32;
    constexpr int RSH = (BK == 64) ? 7 : 6;

    __shared__ ushort_t As[2][2][64 * BK];
    __shared__ ushort_t Bs[2][2][BN * BK];

    const int tid = threadIdx.x, wave = tid >> 6, lane = tid & 63;
    const int n0 = blockIdx.x * BN;
    const int m0 = blockIdx.y * 64;
    const int h  = (MODE == 1) ? blockIdx.z : ((MODE == 2) ? blockIdx.x : 0);
    const int acol = (MODE == 1) ? h * 96 : ((MODE == 2) ? h * 768 : 0);
    const ushort_t* Wb = W + ((MODE == 1) ? (size_t)h * 768 * 96 : (size_t)0);
    const int ocol = (MODE == 1) ? h * 768 : 0;

    const int wr = wave >> 1, wc = wave & 1;
    const int l15 = lane & 15, kg = lane >> 4;

    auto stage = [&](int kt, int buf) {
#pragma unroll
        for (int hl = 0; hl < 2; ++hl) {
            const ushort_t* Ap = A + (hl ? aLo : 0);
            const ushort_t* Wp = Wb + (hl ? wLo : 0);
#pragma unroll
            for (int c = 0; c < CA / 4; ++c) {
                int call = wave + 4 * c;
                int off = call * 1024 + lane * 16;
                int row = off >> RSH;
                int chunk = (off & (2 * BK - 1)) >> 4;
                int sw = chunk ^ (row & (CH - 1));
                const ushort_t* src = Ap + (size_t)(m0 + row) * LDA + acol + kt + sw * 8;
                glds16(src, (char*)As[buf][hl] + call * 1024);
            }
#pragma unroll
            for (int c = 0; c < CB / 4; ++c) {
                int call = wave + 4 * c;
                int off = call * 1024 + lane * 16;
                int row = off >> RSH;
                int chunk = (off & (2 * BK - 1)) >> 4;
                int sw = chunk ^ (row & (CH - 1));
                const ushort_t* src = Wp + (size_t)(n0 + row) * LDW + kt + sw * 8;
                glds16(src, (char*)Bs[buf][hl] + call * 1024);
            }
        }
    };

    f32x4 acc[2][NJ];
#pragma unroll
    for (int i = 0; i < 2; ++i)
#pragma unroll
        for (int j = 0; j < NJ; ++j) acc[i][j] = (f32x4){0.f, 0.f, 0.f, 0.f};

    stage(0, 0);
    int cur = 0;
    for (int s = 0; s < NSTEP; ++s) {
        __builtin_amdgcn_s_barrier();
        if (s + 1 < NSTEP) {
            stage((s + 1) * BK, cur ^ 1);
            asm volatile("s_waitcnt vmcnt(%0)" :: "i"(NC) : "memory");
        } else {
            asm volatile("s_waitcnt vmcnt(0)" ::: "memory");
        }
        __builtin_amdgcn_s_barrier();
        __builtin_amdgcn_sched_barrier(0);

        const ushort_t* ah_ = As[cur][0];
        const ushort_t* al_ = As[cur][1];
        const ushort_t* bh_ = Bs[cur][0];
        const ushort_t* bl_ = Bs[cur][1];
#pragma unroll
        for (int kw = 0; kw < BK / 32; ++kw) {
            const int kb = kw * 4;
            bf16x8 ah[2], al[2], bh[NJ], bl[NJ];
#pragma unroll
            for (int i = 0; i < 2; ++i) {
                int r = wr * 32 + i * 16 + l15;
                int c = (kb + kg) ^ (r & (CH - 1));
                ah[i] = *reinterpret_cast<const bf16x8*>(&ah_[r * BK + c * 8]);
                al[i] = *reinterpret_cast<const bf16x8*>(&al_[r * BK + c * 8]);
            }
#pragma unroll
            for (int j = 0; j < NJ; ++j) {
                int r = wc * WCW + j * 16 + l15;
                int c = (kb + kg) ^ (r & (CH - 1));
                bh[j] = *reinterpret_cast<const bf16x8*>(&bh_[r * BK + c * 8]);
                bl[j] = *reinterpret_cast<const bf16x8*>(&bl_[r * BK + c * 8]);
            }
#pragma unroll
            for (int i = 0; i < 2; ++i)
#pragma unroll
                for (int j = 0; j < NJ; ++j) {
                    acc[i][j] = __builtin_amdgcn_mfma_f32_16x16x32_bf16(al[i], bh[j], acc[i][j], 0, 0, 0);
                    acc[i][j] = __builtin_amdgcn_mfma_f32_16x16x32_bf16(ah[i], bl[j], acc[i][j], 0, 0, 0);
                    acc[i][j] = __builtin_amdgcn_mfma_f32_16x16x32_bf16(ah[i], bh[j], acc[i][j], 0, 0, 0);
                }
        }
        cur ^= 1;
    }

#pragma unroll
    for (int i = 0; i < 2; ++i)
#pragma unroll
        for (int j = 0; j < NJ; ++j) {
            int rg = m0 + wr * 32 + i * 16 + kg * 4;
            int cg = n0 + wc * WCW + j * 16 + l15;
            float bv = bias ? bias[cg] : 0.f;
#pragma unroll
            for (int reg = 0; reg < 4; ++reg) {
                float v = acc[i][j][reg] + bv;
                size_t oi = (size_t)(rg + reg) * LDO + ocol + cg;
                if (OBF) {
                    ushort_t hi, lo; split2(v, hi, lo);
                    ((ushort_t*)outp)[oi] = hi;
                    ((ushort_t*)outp)[oi + oLo] = lo;
                } else {
                    ((float*)outp)[oi] = v;
                }
            }
        }
}

// ---------------------------------------------------------------------------
// Weight conversions (split hi/lo)
// ---------------------------------------------------------------------------
__global__ __launch_bounds__(256)
void cvt3_kernel(const float* __restrict__ wq, const float* __restrict__ wv,
                 const float* __restrict__ wo, ushort_t* __restrict__ dst)
{
    const int bid = blockIdx.x;
    const int w = bid / 1152;
    const int off = (bid - w * 1152) * 2048 + threadIdx.x * 8;
    const float* src = (w == 0) ? wq : (w == 1) ? wv : wo;
    ushort_t hi[8], lo[8];
#pragma unroll
    for (int e = 0; e < 8; ++e) split2(src[off + e], hi[e], lo[e]);
    ushort_t* base = dst + (size_t)w * (2 * WL);
    *reinterpret_cast<uint4*>(base + off) = *reinterpret_cast<uint4*>(hi);
    *reinterpret_cast<uint4*>(base + WL + off) = *reinterpret_cast<uint4*>(lo);
}

// wkT[t][h][n][j] = split(w_k[t][h*96+j][n]).  grid (12 n-tiles, 32 t*h)
__global__ __launch_bounds__(256)
void wkT_kernel(const float* __restrict__ w_k, ushort_t* __restrict__ wkT)
{
    __shared__ float tile[96][65];
    const int n0 = blockIdx.x * 64;
    const int th = blockIdx.y;
    const int t = th >> 3, h = th & 7;
    const float* src = w_k + ((size_t)t * Dv + h * DHv) * Dv + n0;
    for (int idx = threadIdx.x; idx < 96 * 64; idx += 256) {
        int j = idx >> 6, n = idx & 63;
        tile[j][n] = src[(size_t)j * Dv + n];
    }
    __syncthreads();
    for (int idx = threadIdx.x; idx < 64 * 96; idx += 256) {
        int n = idx / 96, j = idx - n * 96;
        ushort_t hi, lo; split2(tile[j][n], hi, lo);
        size_t oi = ((size_t)th * Dv + n0 + n) * DHv + j;
        wkT[oi] = hi; wkT[oi + WL] = lo;
    }
}

// ---------------------------------------------------------------------------
// Precompute 1: twiddle tables + filt means
// ---------------------------------------------------------------------------
__global__ __launch_bounds__(256)
void pre1_kernel(float* __restrict__ twc, float* __restrict__ tws,
                 const float* __restrict__ sr, const float* __restrict__ si,
                 float* __restrict__ filt)
{
    __shared__ float red[8];
    const int bid = blockIdx.x;
    if (bid < 48) {
        int idx = bid * 256 + threadIdx.x;
        int k = idx / Dv, n = idx % Dv;
        int r = (k * n) % Dv;
        float ang = (float)r * (float)(6.283185307179586 / 768.0);
        twc[idx] = cosf(ang);
        tws[idx] = sinf(ang);
    } else {
        int tk = bid - 48;
        const float* a  = sr + (size_t)tk * Dv;
        const float* b2 = si + (size_t)tk * Dv;
        float s1 = 0.f, s2 = 0.f;
#pragma unroll
        for (int j = 0; j < 3; ++j) {
            int c = threadIdx.x + 256 * j;
            s1 += a[c]; s2 += b2[c];
        }
        int wave = threadIdx.x >> 6, lane = threadIdx.x & 63;
#pragma unroll
        for (int dd = 1; dd < 64; dd <<= 1) { s1 += __shfl_xor(s1, dd); s2 += __shfl_xor(s2, dd); }
        if (lane == 0) { red[wave * 2] = s1; red[wave * 2 + 1] = s2; }
        __syncthreads();
        if (threadIdx.x == 0) {
            filt[tk * 2]     = (red[0] + red[2] + red[4] + red[6]) * (1.f / 768.f);
            filt[tk * 2 + 1] = (red[1] + red[3] + red[5] + red[7]) * (1.f / 768.f);
        }
    }
}

// ---------------------------------------------------------------------------
// Precompute 2: folded ifft+proj matrices. One WAVE per (t,i); lane-split
// coalesced dot over n; all 16 modes per wave (proj_w row read once).
// grid 768 blocks x 256 threads (4 waves).
// ---------------------------------------------------------------------------
__global__ __launch_bounds__(256)
void cs_kernel(const float* __restrict__ proj_w, const float* __restrict__ twc,
               const float* __restrict__ tws, float* __restrict__ csC,
               float* __restrict__ csS)
{
    const int wave = threadIdx.x >> 6, lane = threadIdx.x & 63;
    const int gw = blockIdx.x * 4 + wave;   // 0..3071 = t*768 + i
    const int t = gw / 768;
    const int i = gw - t * 768;
    const float* pr = proj_w + ((size_t)t * Dv + i) * Dv + 4 * lane;
    float4 p4[3];
#pragma unroll
    for (int j = 0; j < 3; ++j) p4[j] = ld4(pr + 256 * j);
    for (int k = 0; k < 16; ++k) {
        const float* tc = twc + (size_t)k * Dv + 4 * lane;
        const float* ts = tws + (size_t)k * Dv + 4 * lane;
        float ac = 0.f, as = 0.f;
#pragma unroll
        for (int j = 0; j < 3; ++j) {
            float4 c4 = ld4(tc + 256 * j);
            float4 s4 = ld4(ts + 256 * j);
            ac = fmaf(p4[j].x, c4.x, ac); ac = fmaf(p4[j].y, c4.y, ac);
            ac = fmaf(p4[j].z, c4.z, ac); ac = fmaf(p4[j].w, c4.w, ac);
            as = fmaf(p4[j].x, s4.x, as); as = fmaf(p4[j].y, s4.y, as);
            as = fmaf(p4[j].z, s4.z, as); as = fmaf(p4[j].w, s4.w, as);
        }
#pragma unroll
        for (int dd = 1; dd < 64; dd <<= 1) {
            ac += __shfl_xor(ac, dd);
            as += __shfl_xor(as, dd);
        }
        if (lane == 0) {
            csC[((size_t)t * 16 + k) * Dv + i] = ac * (1.f / 768.f);
            csS[((size_t)t * 16 + k) * Dv + i] = as * (1.f / 768.f);
        }
    }
}

// ---------------------------------------------------------------------------
// Fused: LN1 -> DFT16*filt -> denoise -> LN2 -> gate -> BN -> classify
// ---------------------------------------------------------------------------
__global__ __launch_bounds__(256)
void lnden_kernel(float* __restrict__ z, ushort_t* __restrict__ zbf,
                  const float* __restrict__ za,
                  const float* __restrict__ g1, const float* __restrict__ b1,
                  const float* __restrict__ g2, const float* __restrict__ b2,
                  const float* __restrict__ bng, const float* __restrict__ bnb,
                  const float* __restrict__ gate_p, const float* __restrict__ sa_p,
                  const float* __restrict__ sd_p,
                  const float* __restrict__ twc, const float* __restrict__ tws,
                  const float* __restrict__ filt_t,
                  const float* __restrict__ csC_t, const float* __restrict__ csS_t,
                  const float* __restrict__ pb_t,
                  const float* __restrict__ f1w, const float* __restrict__ f1b,
                  const float* __restrict__ f1g, const float* __restrict__ f1bb,
                  const float* __restrict__ f2w, const float* __restrict__ f2b,
                  const float* __restrict__ f2g, const float* __restrict__ f2bb,
                  const float* __restrict__ clw, const float* __restrict__ clb,
                  float* __restrict__ outp, int t)
{
    const int b = blockIdx.x, tid = threadIdx.x;
    const int wave = tid >> 6, lane = tid & 63;
    __shared__ float red[8];
    __shared__ float dred[4][32];
    __shared__ float fin[32];
    __shared__ float kr[16], ki[16];
    __shared__ float zs[768];
    __shared__ float h1s[256];
    __shared__ float h2s[128];

    const float sa = sa_p[0];
    float v[3], zo[3];
    float s = 0.f, s2 = 0.f;
#pragma unroll
    for (int j = 0; j < 3; ++j) {
        int c = tid + 256 * j;
        zo[j] = z[(size_t)b * Dv + c];
        float val = zo[j] + sa * za[(size_t)b * Dv + c];
        v[j] = val; s += val; s2 += val * val;
    }
#pragma unroll
    for (int dd = 1; dd < 64; dd <<= 1) { s += __shfl_xor(s, dd); s2 += __shfl_xor(s2, dd); }
    if (lane == 0) { red[wave * 2] = s; red[wave * 2 + 1] = s2; }
    __syncthreads();
    {
        const float mean = (red[0] + red[2] + red[4] + red[6]) * (1.f / 768.f);
        const float var  = (red[1] + red[3] + red[5] + red[7]) * (1.f / 768.f) - mean * mean;
        const float rstd = rsqrtf(var + 1e-5f);
#pragma unroll
        for (int j = 0; j < 3; ++j) {
            int c = tid + 256 * j;
            v[j] = (v[j] - mean) * rstd * g1[c] + b1[c];   // v now = z1
        }
    }
    float Fc[16], Fs[16];
#pragma unroll
    for (int k = 0; k < 16; ++k) { Fc[k] = 0.f; Fs[k] = 0.f; }
#pragma unroll
    for (int j = 0; j < 3; ++j) {
        int c = tid + 256 * j;
#pragma unroll
        for (int k = 0; k < 16; ++k) {
            Fc[k] = fmaf(v[j], twc[k * Dv + c], Fc[k]);
            Fs[k] = fmaf(v[j], tws[k * Dv + c], Fs[k]);
        }
    }
#pragma unroll
    for (int dd = 1; dd < 64; dd <<= 1) {
#pragma unroll
        for (int k = 0; k < 16; ++k) { Fc[k] += __shfl_xor(Fc[k], dd); Fs[k] += __shfl_xor(Fs[k], dd); }
    }
    if (lane == 0) {
#pragma unroll
        for (int k = 0; k < 16; ++k) { dred[wave][k] = Fc[k]; dred[wave][16 + k] = Fs[k]; }
    }
    __syncthreads();
    if (tid < 32) fin[tid] = dred[0][tid] + dred[1][tid] + dred[2][tid] + dred[3][tid];
    __syncthreads();
    if (tid < 16) {
        float Sc = fin[tid], Ss = fin[16 + tid];   // fft_k = Sc - i*Ss
        float fr = filt_t[tid * 2], fi = filt_t[tid * 2 + 1];
        kr[tid] = Sc * fr + Ss * fi;
        ki[tid] = Sc * fi - Ss * fr;
    }
    __syncthreads();

    const float sd  = sd_p[0];
    const float gv  = 1.f / (1.f + expf(-gate_p[0]));
    const float bnc = 1.f / sqrtf(1.f + 1e-5f);
    float w3[3];
    s = 0.f; s2 = 0.f;
#pragma unroll
    for (int j = 0; j < 3; ++j) {
        int c = tid + 256 * j;
        float den = pb_t[c];
#pragma unroll
        for (int k = 0; k < 16; ++k) {
            den = fmaf(kr[k], csC_t[k * Dv + c], den);
            den = fmaf(-ki[k], csS_t[k * Dv + c], den);
        }
        float val = v[j] + sd * den;
        w3[j] = val; s += val; s2 += val * val;
    }
#pragma unroll
    for (int dd = 1; dd < 64; dd <<= 1) { s += __shfl_xor(s, dd); s2 += __shfl_xor(s2, dd); }
    if (lane == 0) { red[wave * 2] = s; red[wave * 2 + 1] = s2; }
    __syncthreads();
    const float mean2 = (red[0] + red[2] + red[4] + red[6]) * (1.f / 768.f);
    const float var2  = (red[1] + red[3] + red[5] + red[7]) * (1.f / 768.f) - mean2 * mean2;
    const float rstd2 = rsqrtf(var2 + 1e-5f);
#pragma unroll
    for (int j = 0; j < 3; ++j) {
        int c = tid + 256 * j;
        float z2v = (w3[j] - mean2) * rstd2 * g2[c] + b2[c];
        float z3v = gv * z2v + (1.f - gv) * zo[j];
        float zn  = z3v * (bng[c] * bnc) + bnb[c];
        z[(size_t)b * Dv + c] = zn;
        ushort_t hi, lo; split2(zn, hi, lo);
        zbf[(size_t)b * Dv + c] = hi;
        zbf[(size_t)b * Dv + c + ZL] = lo;
        zs[c] = zn;
    }
    __syncthreads();
    float h = f1b[tid];
    for (int d = 0; d < 768; ++d) h = fmaf(zs[d], f1w[(size_t)d * 256 + tid], h);
    h = h * (f1g[tid] * bnc) + f1bb[tid];
    h1s[tid] = fmaxf(h, 0.f);
    __syncthreads();
    if (tid < 128) {
        float h2 = f2b[tid];
        for (int i2 = 0; i2 < 256; ++i2) h2 = fmaf(h1s[i2], f2w[(size_t)i2 * 128 + tid], h2);
        h2 = h2 * (f2g[tid] * bnc) + f2bb[tid];
        h2s[tid] = fmaxf(h2, 0.f);
    }
    __syncthreads();
    if (tid < NCv) {
        float lg = clb[tid];
        for (int i2 = 0; i2 < 128; ++i2) lg = fmaf(h2s[i2], clw[(size_t)i2 * NCv + tid], lg);
        lg *= 0.25f;
        if (t == 0) outp[(size_t)b * NCv + tid] = lg;
        else        outp[(size_t)b * NCv + tid] += lg;
    }
}

// ---------------------------------------------------------------------------
extern "C" void kernel_launch(void* const* d_in, const int* in_sizes, int n_in,
                              void* d_out, int out_size, void* d_ws, size_t ws_size,
                              hipStream_t stream)
{
    (void)in_sizes; (void)n_in; (void)out_size; (void)ws_size;
    const float* x      = (const float*)d_in[0];
    const float* pool_w = (const float*)d_in[1];
    const float* w_q   = (const float*)d_in[3];
    const float* w_k   = (const float*)d_in[4];
    const float* w_v   = (const float*)d_in[5];
    const float* b_qkv = (const float*)d_in[6];
    const float* w_o   = (const float*)d_in[7];
    const float* b_o   = (const float*)d_in[8];
    const float* ln1_g = (const float*)d_in[9];
    const float* ln1_b = (const float*)d_in[10];
    const float* ln2_g = (const float*)d_in[11];
    const float* ln2_b = (const float*)d_in[12];
    const float* s_re  = (const float*)d_in[13];
    const float* s_im  = (const float*)d_in[14];
    const float* proj_w= (const float*)d_in[15];
    const float* proj_b= (const float*)d_in[16];
    const float* bn_g  = (const float*)d_in[17];
    const float* bn_b  = (const float*)d_in[18];
    const float* gate  = (const float*)d_in[19];
    const float* s_at  = (const float*)d_in[20];
    const float* s_dn  = (const float*)d_in[21];
    const float* f1w   = (const float*)d_in[22];
    const float* f1b   = (const float*)d_in[23];
    const float* f1g   = (const float*)d_in[24];
    const float* f1bb  = (const float*)d_in[25];
    const float* f2w   = (const float*)d_in[26];
    const float* f2b   = (const float*)d_in[27];
    const float* f2g   = (const float*)d_in[28];
    const float* f2bb  = (const float*)d_in[29];
    const float* clw   = (const float*)d_in[30];
    const float* clb   = (const float*)d_in[31];
    float* out = (float*)d_out;

    // ws layout (floats first, then ushort planes)
    float* ws   = (float*)d_ws;
    float* twc  = ws;                       // 12288
    float* tws  = twc + 12288;              // 12288
    float* filt = tws + 12288;              // 128
    float* csC  = filt + 128;               // 49152
    float* csS  = csC + 49152;              // 49152
    float* z    = csS + 49152;              // 196608
    float* za   = z + 196608;               // 196608
    float* Qk   = za + 196608;              // 1572864
    float* pacc = Qk + 1572864;             // 6291456 (max(pool 16*B*D, attn 4*B*H*D))
    float* pmlf = pacc + 6291456;           // 16384
    ushort_t* xbf  = (ushort_t*)(pmlf + 16384);  // 100663296
    ushort_t* zbf  = xbf + 100663296;       // 2*196608 (hi,lo)
    ushort_t* qbf  = zbf + 2 * ZL;          // 2*196608
    ushort_t* xwbf = qbf + 2 * ZL;          // 2*1572864
    ushort_t* obf  = xwbf + 2 * XWL;        // 2*196608
    ushort_t* wspl = obf + 2 * ZL;          // 3 * 2*WL (wq,wv,wo hi/lo)
    ushort_t* wkT  = wspl + 6 * WL;         // 2*WL
    float2* pml = (float2*)pmlf;
    ushort_t* wqbf = wspl;
    ushort_t* wvbf = wspl + 2 * WL;
    ushort_t* wobf = wspl + 4 * WL;

    pre1_kernel<<<112, 256, 0, stream>>>(twc, tws, s_re, s_im, filt);
    cs_kernel<<<768, 256, 0, stream>>>(proj_w, twc, tws, csC, csS);
    cvt3_kernel<<<3456, 256, 0, stream>>>(w_q, w_v, w_o, wspl);
    wkT_kernel<<<dim3(12, 32), 256, 0, stream>>>(w_k, wkT);

    pool_cvt_kernel<<<dim3(256, 2), 512, 0, stream>>>(x, pool_w, xbf, pacc, pml);
    merge_kernel<1, 16, true><<<256, 256, 0, stream>>>(pacc, pml, zbf, ZL, z);

    const float iscale = (float)(1.0 / sqrt(96.0));
    for (int t = 0; t < 4; ++t) {
        // q = z @ w_q[t]^T + bq  -> split bf16
        mgemm_kernel<0, true><<<dim3(12, 4), 256, 0, stream>>>(
            zbf, ZL, wqbf + (size_t)t * WT, WL, b_qkv + (size_t)t * 2304, qbf, ZL);
        // Qk[b,h,:] = q_h @ wkT[t,h] -> f32
        mgemm_kernel<1, false><<<dim3(12, 4, 8), 256, 0, stream>>>(
            qbf, ZL, wkT + (size_t)t * WT, WL, nullptr, Qk, 0);
        // attention stream over bf16 x (no-LDS, 3-stage pipeline)
        attn_flash_kernel<<<dim3(256, 2), 512, 0, stream>>>(xbf, Qk, pacc, pml, iscale);
        merge_kernel<8, 4, false><<<256, 256, 0, stream>>>(pacc, pml, xwbf, XWL, nullptr);
        // o = W_v[t] xw(head) + bv -> split bf16
        mgemm_kernel<2, true><<<dim3(8, 4), 256, 0, stream>>>(
            xwbf, XWL, wvbf + (size_t)t * WT, WL, b_qkv + (size_t)t * 2304 + 1536, obf, ZL);
        // za = o @ w_o[t]^T + bo -> f32
        mgemm_kernel<0, false><<<dim3(12, 4), 256, 0, stream>>>(
            obf, ZL, wobf + (size_t)t * WT, WL, b_o + (size_t)t * Dv, za, 0);
        // fused LN1/DFT/denoise/LN2/gate/BN/classify
        lnden_kernel<<<256, 256, 0, stream>>>(
            z, zbf, za,
            ln1_g + (size_t)t * Dv, ln1_b + (size_t)t * Dv,
            ln2_g + (size_t)t * Dv, ln2_b + (size_t)t * Dv,
            bn_g + (size_t)t * Dv, bn_b + (size_t)t * Dv,
            gate + t, s_at + t, s_dn + t,
            twc, tws, filt + (size_t)t * 32,
            csC + (size_t)t * 12288, csS + (size_t)t * 12288,
            proj_b + (size_t)t * Dv,
            f1w, f1b, f1g, f1bb, f2w, f2b, f2g, f2bb,
            clw, clb, out, t);
    }
}

// Round 11
// 930.261 us; speedup vs baseline: 1.2017x; 1.2017x over previous
//
#include <hip/hip_runtime.h>
#include <math.h>

// ---------------------------------------------------------------------------
// NoPropDTEncoder forward, round 11:
//  - attn: exact round-9 version (2-deep register prefetch, ~110 VGPR, no
//    spill). Round-10's 3-stage pipeline overflowed the 128-VGPR cap ->
//    scratch spill regression; reverted.
//  - cs_kernel: keep round-10 coalescing fix (wave-per-(t,i), proj_w once)
//  - rest identical to round 9
// ---------------------------------------------------------------------------

#define DEV __device__ __forceinline__

typedef unsigned int   uint32;
typedef unsigned short ushort_t;
typedef __attribute__((ext_vector_type(8))) short bf16x8;
typedef __attribute__((ext_vector_type(4))) float f32x4;
typedef __attribute__((ext_vector_type(2))) float f32x2;

constexpr int Bv  = 256;
constexpr int Sv  = 512;
constexpr int Dv  = 768;
constexpr int Hv  = 8;
constexpr int DHv = 96;
constexpr int NCv = 14;

constexpr size_t ZL  = 196608;     // lo-plane offset for z/q/o (B*D)
constexpr size_t XWL = 1572864;    // lo-plane offset for xw (B*H*D)
constexpr size_t WL  = 2359296;    // lo-plane offset for weights (4*768*768)
constexpr size_t WT  = 589824;     // per-t weight slice (768*768)

DEV float4 ld4(const float* p) { return *reinterpret_cast<const float4*>(p); }

DEV ushort_t f2bf(float f) {
    uint32 u = __float_as_uint(f);
    u += 0x7FFFu + ((u >> 16) & 1u);
    return (ushort_t)(u >> 16);
}
DEV float bf2f(ushort_t h) { return __uint_as_float((uint32)h << 16); }
DEV void split2(float f, ushort_t& hi, ushort_t& lo) {
    hi = f2bf(f);
    lo = f2bf(f - bf2f(hi));
}
DEV uint2 pack4(float4 v) {
    return make_uint2((uint32)f2bf(v.x) | ((uint32)f2bf(v.y) << 16),
                      (uint32)f2bf(v.z) | ((uint32)f2bf(v.w) << 16));
}

// unpack a bf16 pair (packed in uint32) to f32x2
DEV f32x2 bfpair(uint32 u) {
    f32x2 r;
    r.x = __uint_as_float(u << 16);
    r.y = __uint_as_float(u & 0xFFFF0000u);
    return r;
}

// packed fp32 FMA (gfx90a+ v_pk_fma_f32): d = a*b + c on both halves
DEV f32x2 pkfma(f32x2 a, f32x2 b, f32x2 c) {
    f32x2 d;
    asm("v_pk_fma_f32 %0, %1, %2, %3" : "=v"(d) : "v"(a), "v"(b), "v"(c));
    return d;
}

DEV void glds16(const void* g, void* l) {
    __builtin_amdgcn_global_load_lds(
        (const __attribute__((address_space(1))) void*)g,
        (__attribute__((address_space(3))) void*)l, 16, 0, 0);
}

// ---------------------------------------------------------------------------
// Pooling + x->bf16 conversion. grid (B, 2). Partials -> ws (NP=16, NH=1).
// ---------------------------------------------------------------------------
__global__ __launch_bounds__(512, 4)
void pool_cvt_kernel(const float* __restrict__ x, const float* __restrict__ pool_w,
                     ushort_t* __restrict__ xbf,
                     float* __restrict__ pacc, float2* __restrict__ pml)
{
    __shared__ float qks[Dv];
    const int b = blockIdx.x, half = blockIdx.y;
    const int tid = threadIdx.x, wave = tid >> 6, lane = tid & 63;
    for (int i = tid; i < Dv / 4; i += 512)
        *reinterpret_cast<float4*>(&qks[i * 4]) = ld4(pool_w + i * 4);
    __syncthreads();

    const int row0 = half * 256 + wave * 32;
    const float* base = x + ((size_t)b * Sv + row0) * Dv + 4 * lane;

    float4 acc[3];
#pragma unroll
    for (int j = 0; j < 3; ++j) acc[j] = make_float4(0.f, 0.f, 0.f, 0.f);
    float m = -INFINITY, l = 0.f;

    float4 c0[3], c1[3];
#pragma unroll
    for (int j = 0; j < 3; ++j) { c0[j] = ld4(base + 256 * j); c1[j] = ld4(base + Dv + 256 * j); }

    for (int it = 0; it < 16; ++it) {
        float4 n0_[3], n1_[3];
        if (it < 15) {
            const float* nb = base + (size_t)(2 * it + 2) * Dv;
#pragma unroll
            for (int j = 0; j < 3; ++j) { n0_[j] = ld4(nb + 256 * j); n1_[j] = ld4(nb + Dv + 256 * j); }
        }
        ushort_t* ob = xbf + ((size_t)b * Sv + row0 + 2 * it) * Dv + 4 * lane;
#pragma unroll
        for (int j = 0; j < 3; ++j) *reinterpret_cast<uint2*>(ob + 256 * j) = pack4(c0[j]);
#pragma unroll
        for (int j = 0; j < 3; ++j) *reinterpret_cast<uint2*>(ob + Dv + 256 * j) = pack4(c1[j]);
        float p0 = 0.f, p1 = 0.f;
#pragma unroll
        for (int j = 0; j < 3; ++j) {
            const float4 q4 = *reinterpret_cast<const float4*>(&qks[4 * lane + 256 * j]);
            p0 = fmaf(q4.x, c0[j].x, p0); p0 = fmaf(q4.y, c0[j].y, p0);
            p0 = fmaf(q4.z, c0[j].z, p0); p0 = fmaf(q4.w, c0[j].w, p0);
            p1 = fmaf(q4.x, c1[j].x, p1); p1 = fmaf(q4.y, c1[j].y, p1);
            p1 = fmaf(q4.z, c1[j].z, p1); p1 = fmaf(q4.w, c1[j].w, p1);
        }
#pragma unroll
        for (int dd = 1; dd < 64; dd <<= 1) { p0 += __shfl_xor(p0, dd); p1 += __shfl_xor(p1, dd); }
        float mx = fmaxf(p0, p1);
        if (mx > m) {
            float r = __expf(m - mx); l *= r;
#pragma unroll
            for (int j = 0; j < 3; ++j) { acc[j].x *= r; acc[j].y *= r; acc[j].z *= r; acc[j].w *= r; }
            m = mx;
        }
        float w0 = __expf(p0 - m), w1 = __expf(p1 - m);
        l += w0 + w1;
#pragma unroll
        for (int j = 0; j < 3; ++j) {
            acc[j].x = fmaf(w1, c1[j].x, fmaf(w0, c0[j].x, acc[j].x));
            acc[j].y = fmaf(w1, c1[j].y, fmaf(w0, c0[j].y, acc[j].y));
            acc[j].z = fmaf(w1, c1[j].z, fmaf(w0, c0[j].z, acc[j].z));
            acc[j].w = fmaf(w1, c1[j].w, fmaf(w0, c0[j].w, acc[j].w));
        }
        if (it < 15) {
#pragma unroll
            for (int j = 0; j < 3; ++j) { c0[j] = n0_[j]; c1[j] = n1_[j]; }
        }
    }
    const int p = half * 8 + wave;
    const size_t pidx = (size_t)p * 256 + b;
#pragma unroll
    for (int j = 0; j < 3; ++j)
        *reinterpret_cast<float4*>(&pacc[pidx * Dv + 4 * lane + 256 * j]) = acc[j];
    if (lane == 0) pml[pidx] = make_float2(m, l);
}

// ---------------------------------------------------------------------------
// Attention streaming pass (bf16 x). grid (B, 2). Wave w: heads {2(w&3),
// 2(w&3)+1}, rows [half*256 + (w>>2)*128, +128). No LDS, no barriers;
// coalesced uint2 global loads, register pair-double-buffer, pk_fma,
// fold-4 reduce (2 rows x 2 heads). Partials NP=4 (p = half*2 + slice).
// (exact round-9 version — measured good, no spill)
// ---------------------------------------------------------------------------
__global__ __launch_bounds__(512, 4)
void attn_flash_kernel(const ushort_t* __restrict__ xbf, const float* __restrict__ Qk,
                       float* __restrict__ pacc, float2* __restrict__ pml, float scale)
{
    const int b = blockIdx.x, half = blockIdx.y;
    const int tid = threadIdx.x, wave = tid >> 6, lane = tid & 63;
    const int hg = wave & 3, slice = wave >> 2;
    const int h0 = 2 * hg, h1 = h0 + 1;
    const int row0 = half * 256 + slice * 128;

    // q for both heads: 6 f32x2 pairs each, cols {seg*256+4l .. +4}
    f32x2 q0[6], q1[6];
    {
        const float* qp0 = Qk + ((size_t)b * Hv + h0) * Dv + 4 * lane;
        const float* qp1 = Qk + ((size_t)b * Hv + h1) * Dv + 4 * lane;
#pragma unroll
        for (int s = 0; s < 3; ++s) {
            float4 a = ld4(qp0 + s * 256);
            float4 c = ld4(qp1 + s * 256);
            q0[2 * s]     = (f32x2){a.x, a.y}; q0[2 * s + 1] = (f32x2){a.z, a.w};
            q1[2 * s]     = (f32x2){c.x, c.y}; q1[2 * s + 1] = (f32x2){c.z, c.w};
        }
    }
    f32x2 a0[6], a1[6];
#pragma unroll
    for (int c = 0; c < 6; ++c) { a0[c] = (f32x2){0.f, 0.f}; a1[c] = (f32x2){0.f, 0.f}; }
    float m0 = -INFINITY, l0 = 0.f, m1 = -INFINITY, l1 = 0.f;

    const ushort_t* base = xbf + ((size_t)b * Sv + row0) * Dv + 4 * lane;

    uint2 c0[3], c1[3];
#pragma unroll
    for (int s = 0; s < 3; ++s) {
        c0[s] = *reinterpret_cast<const uint2*>(base + s * 256);
        c1[s] = *reinterpret_cast<const uint2*>(base + Dv + s * 256);
    }

    for (int it = 0; it < 64; ++it) {
        uint2 n0[3], n1[3];
        if (it < 63) {
            const ushort_t* nb = base + (size_t)(2 * it + 2) * Dv;
#pragma unroll
            for (int s = 0; s < 3; ++s) {
                n0[s] = *reinterpret_cast<const uint2*>(nb + s * 256);
                n1[s] = *reinterpret_cast<const uint2*>(nb + Dv + s * 256);
            }
        }
        // unpack both rows
        f32x2 xf0[6], xf1[6];
#pragma unroll
        for (int s = 0; s < 3; ++s) {
            xf0[2 * s] = bfpair(c0[s].x); xf0[2 * s + 1] = bfpair(c0[s].y);
            xf1[2 * s] = bfpair(c1[s].x); xf1[2 * s + 1] = bfpair(c1[s].y);
        }
        // scores: 2 rows x 2 heads
        f32x2 t00 = (f32x2){0.f, 0.f}, t01 = t00, t10 = t00, t11 = t00;
#pragma unroll
        for (int c = 0; c < 6; ++c) {
            t00 = pkfma(xf0[c], q0[c], t00);
            t01 = pkfma(xf0[c], q1[c], t01);
            t10 = pkfma(xf1[c], q0[c], t10);
            t11 = pkfma(xf1[c], q1[c], t11);
        }
        float s4[4];
        s4[0] = t00.x + t00.y;   // row0, h0
        s4[1] = t01.x + t01.y;   // row0, h1
        s4[2] = t10.x + t10.y;   // row1, h0
        s4[3] = t11.x + t11.y;   // row1, h1
        // ---- folded reduce: 4 values over 64 lanes, broadcast (r8-verified) ----
        {
            const bool k0 = (lane & 1), k1 = (lane & 2);
            float sd0 = k0 ? s4[0] : s4[1];
            float rc0 = __shfl_xor(sd0, 1);
            float t0  = (k0 ? s4[1] : s4[0]) + rc0;
            float sd1 = k0 ? s4[2] : s4[3];
            float rc1 = __shfl_xor(sd1, 1);
            float t1  = (k0 ? s4[3] : s4[2]) + rc1;
            float sd2 = k1 ? t0 : t1;
            float rc2 = __shfl_xor(sd2, 2);
            float u   = (k1 ? t1 : t0) + rc2;
            u += __shfl_xor(u, 4);  u += __shfl_xor(u, 8);
            u += __shfl_xor(u, 16); u += __shfl_xor(u, 32);
            float b1 = __shfl_xor(u, 1);
            float b2 = __shfl_xor(u, 2);
            float b3 = __shfl_xor(u, 3);
            s4[0] = k1 ? (k0 ? b3 : b2) : (k0 ? b1 : u);
            s4[1] = k1 ? (k0 ? b2 : b3) : (k0 ? u  : b1);
            s4[2] = k1 ? (k0 ? b1 : u ) : (k0 ? b3 : b2);
            s4[3] = k1 ? (k0 ? u  : b1) : (k0 ? b2 : b3);
        }
#pragma unroll
        for (int j = 0; j < 4; ++j) s4[j] *= scale;
        // head 0 (rows: s4[0], s4[2])
        {
            float mx = fmaxf(s4[0], s4[2]);
            if (mx > m0) {
                float f = __expf(m0 - mx); l0 *= f;
#pragma unroll
                for (int c = 0; c < 6; ++c) { a0[c].x *= f; a0[c].y *= f; }
                m0 = mx;
            }
            float w0 = __expf(s4[0] - m0), w1 = __expf(s4[2] - m0);
            l0 += w0 + w1;
            f32x2 w02 = (f32x2){w0, w0}, w12 = (f32x2){w1, w1};
#pragma unroll
            for (int c = 0; c < 6; ++c) a0[c] = pkfma(xf1[c], w12, pkfma(xf0[c], w02, a0[c]));
        }
        // head 1 (rows: s4[1], s4[3])
        {
            float mx = fmaxf(s4[1], s4[3]);
            if (mx > m1) {
                float f = __expf(m1 - mx); l1 *= f;
#pragma unroll
                for (int c = 0; c < 6; ++c) { a1[c].x *= f; a1[c].y *= f; }
                m1 = mx;
            }
            float w0 = __expf(s4[1] - m1), w1 = __expf(s4[3] - m1);
            l1 += w0 + w1;
            f32x2 w02 = (f32x2){w0, w0}, w12 = (f32x2){w1, w1};
#pragma unroll
            for (int c = 0; c < 6; ++c) a1[c] = pkfma(xf1[c], w12, pkfma(xf0[c], w02, a1[c]));
        }
        if (it < 63) {
#pragma unroll
            for (int s = 0; s < 3; ++s) { c0[s] = n0[s]; c1[s] = n1[s]; }
        }
    }

    const int p = half * 2 + slice;
    const size_t pidx0 = ((size_t)p * 256 + b) * Hv + h0;
    const size_t pidx1 = pidx0 + 1;
    float* pb0 = pacc + pidx0 * Dv + 4 * lane;
    float* pb1 = pacc + pidx1 * Dv + 4 * lane;
#pragma unroll
    for (int s = 0; s < 3; ++s) {
        *reinterpret_cast<float4*>(pb0 + s * 256) =
            make_float4(a0[2 * s].x, a0[2 * s].y, a0[2 * s + 1].x, a0[2 * s + 1].y);
        *reinterpret_cast<float4*>(pb1 + s * 256) =
            make_float4(a1[2 * s].x, a1[2 * s].y, a1[2 * s + 1].x, a1[2 * s + 1].y);
    }
    if (lane == 0) {
        pml[pidx0] = make_float2(m0, l0);
        pml[pidx1] = make_float2(m1, l1);
    }
}

// ---------------------------------------------------------------------------
// Merge NP partials -> split bf16 (hi at obf, lo at obf+loOff), opt f32.
// ---------------------------------------------------------------------------
template<int NH, int NP, bool WF32>
__global__ __launch_bounds__(256)
void merge_kernel(const float* __restrict__ pacc, const float2* __restrict__ pml,
                  ushort_t* __restrict__ obf, size_t loOff, float* __restrict__ of32)
{
    __shared__ float eS[NH * NP];
    const int b = blockIdx.x, tid = threadIdx.x;
    if (tid < NH) {
        float2 mls[NP];
        float mm = -INFINITY;
#pragma unroll
        for (int p = 0; p < NP; ++p) {
            mls[p] = pml[((size_t)p * 256 + b) * NH + tid];
            mm = fmaxf(mm, mls[p].x);
        }
        float ee[NP]; float L = 0.f;
#pragma unroll
        for (int p = 0; p < NP; ++p) { ee[p] = __expf(mls[p].x - mm); L += mls[p].y * ee[p]; }
        float inv = 1.f / L;
#pragma unroll
        for (int p = 0; p < NP; ++p) eS[tid * NP + p] = ee[p] * inv;
    }
    __syncthreads();
#pragma unroll
    for (int seg = 0; seg < NH * 3; ++seg) {
        int h = seg / 3;
        int d = (seg - h * 3) * 256 + tid;
        float v = 0.f;
#pragma unroll
        for (int p = 0; p < NP; ++p)
            v += pacc[((size_t)((size_t)p * 256 + b) * NH + h) * Dv + d] * eS[h * NP + p];
        size_t oi = ((size_t)b * NH + h) * Dv + d;
        ushort_t hi, lo; split2(v, hi, lo);
        obf[oi] = hi; obf[oi + loOff] = lo;
        if (WF32) of32[oi] = v;
    }
}

// ---------------------------------------------------------------------------
// SPLIT-bf16 MFMA GEMM: out[m,n] = bias[n] + sum_k A[m,k]*W[n,k], A,W as
// hi/lo pairs. MODE 0: BN=64 BK=64 K=768; MODE 1: BN=64 BK=32 K=96
// grid.z=head; MODE 2: BN=96 BK=64 K=768, h=n0/96, A col offset h*768.
// ---------------------------------------------------------------------------
template<int MODE, bool OBF>
__global__ __launch_bounds__(256)
void mgemm_kernel(const ushort_t* __restrict__ A, size_t aLo,
                  const ushort_t* __restrict__ W, size_t wLo,
                  const float* __restrict__ bias, void* __restrict__ outp,
                  size_t oLo)
{
    constexpr int BN = (MODE == 2) ? 96 : 64;
    constexpr int BK = (MODE == 1) ? 32 : 64;
    constexpr int NJ = BN / 32;
    constexpr int KTOT = (MODE == 1) ? 96 : 768;
    constexpr int NSTEP = KTOT / BK;
    constexpr int CH = BK / 8;
    constexpr int CA = (64 * BK) / 512;
    constexpr int CB = (BN * BK) / 512;
    constexpr int NC = 2 * (CA + CB) / 4;    // per-wave glds calls per stage
    constexpr int LDA = (MODE == 2) ? 6144 : 768;
    constexpr int LDW = (MODE == 1) ? 96 : 768;
    constexpr int LDO = (MODE == 1) ? 6144 : 768;
    constexpr int WCW = (MODE == 2) ? 48 : 32;
    constexpr int RSH = (BK == 64) ? 7 : 6;

    __shared__ ushort_t As[2][2][64 * BK];
    __shared__ ushort_t Bs[2][2][BN * BK];

    const int tid = threadIdx.x, wave = tid >> 6, lane = tid & 63;
    const int n0 = blockIdx.x * BN;
    const int m0 = blockIdx.y * 64;
    const int h  = (MODE == 1) ? blockIdx.z : ((MODE == 2) ? blockIdx.x : 0);
    const int acol = (MODE == 1) ? h * 96 : ((MODE == 2) ? h * 768 : 0);
    const ushort_t* Wb = W + ((MODE == 1) ? (size_t)h * 768 * 96 : (size_t)0);
    const int ocol = (MODE == 1) ? h * 768 : 0;

    const int wr = wave >> 1, wc = wave & 1;
    const int l15 = lane & 15, kg = lane >> 4;

    auto stage = [&](int kt, int buf) {
#pragma unroll
        for (int hl = 0; hl < 2; ++hl) {
            const ushort_t* Ap = A + (hl ? aLo : 0);
            const ushort_t* Wp = Wb + (hl ? wLo : 0);
#pragma unroll
            for (int c = 0; c < CA / 4; ++c) {
                int call = wave + 4 * c;
                int off = call * 1024 + lane * 16;
                int row = off >> RSH;
                int chunk = (off & (2 * BK - 1)) >> 4;
                int sw = chunk ^ (row & (CH - 1));
                const ushort_t* src = Ap + (size_t)(m0 + row) * LDA + acol + kt + sw * 8;
                glds16(src, (char*)As[buf][hl] + call * 1024);
            }
#pragma unroll
            for (int c = 0; c < CB / 4; ++c) {
                int call = wave + 4 * c;
                int off = call * 1024 + lane * 16;
                int row = off >> RSH;
                int chunk = (off & (2 * BK - 1)) >> 4;
                int sw = chunk ^ (row & (CH - 1));
                const ushort_t* src = Wp + (size_t)(n0 + row) * LDW + kt + sw * 8;
                glds16(src, (char*)Bs[buf][hl] + call * 1024);
            }
        }
    };

    f32x4 acc[2][NJ];
#pragma unroll
    for (int i = 0; i < 2; ++i)
#pragma unroll
        for (int j = 0; j < NJ; ++j) acc[i][j] = (f32x4){0.f, 0.f, 0.f, 0.f};

    stage(0, 0);
    int cur = 0;
    for (int s = 0; s < NSTEP; ++s) {
        __builtin_amdgcn_s_barrier();
        if (s + 1 < NSTEP) {
            stage((s + 1) * BK, cur ^ 1);
            asm volatile("s_waitcnt vmcnt(%0)" :: "i"(NC) : "memory");
        } else {
            asm volatile("s_waitcnt vmcnt(0)" ::: "memory");
        }
        __builtin_amdgcn_s_barrier();
        __builtin_amdgcn_sched_barrier(0);

        const ushort_t* ah_ = As[cur][0];
        const ushort_t* al_ = As[cur][1];
        const ushort_t* bh_ = Bs[cur][0];
        const ushort_t* bl_ = Bs[cur][1];
#pragma unroll
        for (int kw = 0; kw < BK / 32; ++kw) {
            const int kb = kw * 4;
            bf16x8 ah[2], al[2], bh[NJ], bl[NJ];
#pragma unroll
            for (int i = 0; i < 2; ++i) {
                int r = wr * 32 + i * 16 + l15;
                int c = (kb + kg) ^ (r & (CH - 1));
                ah[i] = *reinterpret_cast<const bf16x8*>(&ah_[r * BK + c * 8]);
                al[i] = *reinterpret_cast<const bf16x8*>(&al_[r * BK + c * 8]);
            }
#pragma unroll
            for (int j = 0; j < NJ; ++j) {
                int r = wc * WCW + j * 16 + l15;
                int c = (kb + kg) ^ (r & (CH - 1));
                bh[j] = *reinterpret_cast<const bf16x8*>(&bh_[r * BK + c * 8]);
                bl[j] = *reinterpret_cast<const bf16x8*>(&bl_[r * BK + c * 8]);
            }
#pragma unroll
            for (int i = 0; i < 2; ++i)
#pragma unroll
                for (int j = 0; j < NJ; ++j) {
                    acc[i][j] = __builtin_amdgcn_mfma_f32_16x16x32_bf16(al[i], bh[j], acc[i][j], 0, 0, 0);
                    acc[i][j] = __builtin_amdgcn_mfma_f32_16x16x32_bf16(ah[i], bl[j], acc[i][j], 0, 0, 0);
                    acc[i][j] = __builtin_amdgcn_mfma_f32_16x16x32_bf16(ah[i], bh[j], acc[i][j], 0, 0, 0);
                }
        }
        cur ^= 1;
    }

#pragma unroll
    for (int i = 0; i < 2; ++i)
#pragma unroll
        for (int j = 0; j < NJ; ++j) {
            int rg = m0 + wr * 32 + i * 16 + kg * 4;
            int cg = n0 + wc * WCW + j * 16 + l15;
            float bv = bias ? bias[cg] : 0.f;
#pragma unroll
            for (int reg = 0; reg < 4; ++reg) {
                float v = acc[i][j][reg] + bv;
                size_t oi = (size_t)(rg + reg) * LDO + ocol + cg;
                if (OBF) {
                    ushort_t hi, lo; split2(v, hi, lo);
                    ((ushort_t*)outp)[oi] = hi;
                    ((ushort_t*)outp)[oi + oLo] = lo;
                } else {
                    ((float*)outp)[oi] = v;
                }
            }
        }
}

// ---------------------------------------------------------------------------
// Weight conversions (split hi/lo)
// ---------------------------------------------------------------------------
__global__ __launch_bounds__(256)
void cvt3_kernel(const float* __restrict__ wq, const float* __restrict__ wv,
                 const float* __restrict__ wo, ushort_t* __restrict__ dst)
{
    const int bid = blockIdx.x;
    const int w = bid / 1152;
    const int off = (bid - w * 1152) * 2048 + threadIdx.x * 8;
    const float* src = (w == 0) ? wq : (w == 1) ? wv : wo;
    ushort_t hi[8], lo[8];
#pragma unroll
    for (int e = 0; e < 8; ++e) split2(src[off + e], hi[e], lo[e]);
    ushort_t* base = dst + (size_t)w * (2 * WL);
    *reinterpret_cast<uint4*>(base + off) = *reinterpret_cast<uint4*>(hi);
    *reinterpret_cast<uint4*>(base + WL + off) = *reinterpret_cast<uint4*>(lo);
}

// wkT[t][h][n][j] = split(w_k[t][h*96+j][n]).  grid (12 n-tiles, 32 t*h)
__global__ __launch_bounds__(256)
void wkT_kernel(const float* __restrict__ w_k, ushort_t* __restrict__ wkT)
{
    __shared__ float tile[96][65];
    const int n0 = blockIdx.x * 64;
    const int th = blockIdx.y;
    const int t = th >> 3, h = th & 7;
    const float* src = w_k + ((size_t)t * Dv + h * DHv) * Dv + n0;
    for (int idx = threadIdx.x; idx < 96 * 64; idx += 256) {
        int j = idx >> 6, n = idx & 63;
        tile[j][n] = src[(size_t)j * Dv + n];
    }
    __syncthreads();
    for (int idx = threadIdx.x; idx < 64 * 96; idx += 256) {
        int n = idx / 96, j = idx - n * 96;
        ushort_t hi, lo; split2(tile[j][n], hi, lo);
        size_t oi = ((size_t)th * Dv + n0 + n) * DHv + j;
        wkT[oi] = hi; wkT[oi + WL] = lo;
    }
}

// ---------------------------------------------------------------------------
// Precompute 1: twiddle tables + filt means
// ---------------------------------------------------------------------------
__global__ __launch_bounds__(256)
void pre1_kernel(float* __restrict__ twc, float* __restrict__ tws,
                 const float* __restrict__ sr, const float* __restrict__ si,
                 float* __restrict__ filt)
{
    __shared__ float red[8];
    const int bid = blockIdx.x;
    if (bid < 48) {
        int idx = bid * 256 + threadIdx.x;
        int k = idx / Dv, n = idx % Dv;
        int r = (k * n) % Dv;
        float ang = (float)r * (float)(6.283185307179586 / 768.0);
        twc[idx] = cosf(ang);
        tws[idx] = sinf(ang);
    } else {
        int tk = bid - 48;
        const float* a  = sr + (size_t)tk * Dv;
        const float* b2 = si + (size_t)tk * Dv;
        float s1 = 0.f, s2 = 0.f;
#pragma unroll
        for (int j = 0; j < 3; ++j) {
            int c = threadIdx.x + 256 * j;
            s1 += a[c]; s2 += b2[c];
        }
        int wave = threadIdx.x >> 6, lane = threadIdx.x & 63;
#pragma unroll
        for (int dd = 1; dd < 64; dd <<= 1) { s1 += __shfl_xor(s1, dd); s2 += __shfl_xor(s2, dd); }
        if (lane == 0) { red[wave * 2] = s1; red[wave * 2 + 1] = s2; }
        __syncthreads();
        if (threadIdx.x == 0) {
            filt[tk * 2]     = (red[0] + red[2] + red[4] + red[6]) * (1.f / 768.f);
            filt[tk * 2 + 1] = (red[1] + red[3] + red[5] + red[7]) * (1.f / 768.f);
        }
    }
}

// ---------------------------------------------------------------------------
// Precompute 2: folded ifft+proj matrices. One WAVE per (t,i); lane-split
// coalesced dot over n; all 16 modes per wave (proj_w row read once).
// grid 768 blocks x 256 threads (4 waves).
// ---------------------------------------------------------------------------
__global__ __launch_bounds__(256)
void cs_kernel(const float* __restrict__ proj_w, const float* __restrict__ twc,
               const float* __restrict__ tws, float* __restrict__ csC,
               float* __restrict__ csS)
{
    const int wave = threadIdx.x >> 6, lane = threadIdx.x & 63;
    const int gw = blockIdx.x * 4 + wave;   // 0..3071 = t*768 + i
    const int t = gw / 768;
    const int i = gw - t * 768;
    const float* pr = proj_w + ((size_t)t * Dv + i) * Dv + 4 * lane;
    float4 p4[3];
#pragma unroll
    for (int j = 0; j < 3; ++j) p4[j] = ld4(pr + 256 * j);
    for (int k = 0; k < 16; ++k) {
        const float* tc = twc + (size_t)k * Dv + 4 * lane;
        const float* ts = tws + (size_t)k * Dv + 4 * lane;
        float ac = 0.f, as = 0.f;
#pragma unroll
        for (int j = 0; j < 3; ++j) {
            float4 c4 = ld4(tc + 256 * j);
            float4 s4 = ld4(ts + 256 * j);
            ac = fmaf(p4[j].x, c4.x, ac); ac = fmaf(p4[j].y, c4.y, ac);
            ac = fmaf(p4[j].z, c4.z, ac); ac = fmaf(p4[j].w, c4.w, ac);
            as = fmaf(p4[j].x, s4.x, as); as = fmaf(p4[j].y, s4.y, as);
            as = fmaf(p4[j].z, s4.z, as); as = fmaf(p4[j].w, s4.w, as);
        }
#pragma unroll
        for (int dd = 1; dd < 64; dd <<= 1) {
            ac += __shfl_xor(ac, dd);
            as += __shfl_xor(as, dd);
        }
        if (lane == 0) {
            csC[((size_t)t * 16 + k) * Dv + i] = ac * (1.f / 768.f);
            csS[((size_t)t * 16 + k) * Dv + i] = as * (1.f / 768.f);
        }
    }
}

// ---------------------------------------------------------------------------
// Fused: LN1 -> DFT16*filt -> denoise -> LN2 -> gate -> BN -> classify
// ---------------------------------------------------------------------------
__global__ __launch_bounds__(256)
void lnden_kernel(float* __restrict__ z, ushort_t* __restrict__ zbf,
                  const float* __restrict__ za,
                  const float* __restrict__ g1, const float* __restrict__ b1,
                  const float* __restrict__ g2, const float* __restrict__ b2,
                  const float* __restrict__ bng, const float* __restrict__ bnb,
                  const float* __restrict__ gate_p, const float* __restrict__ sa_p,
                  const float* __restrict__ sd_p,
                  const float* __restrict__ twc, const float* __restrict__ tws,
                  const float* __restrict__ filt_t,
                  const float* __restrict__ csC_t, const float* __restrict__ csS_t,
                  const float* __restrict__ pb_t,
                  const float* __restrict__ f1w, const float* __restrict__ f1b,
                  const float* __restrict__ f1g, const float* __restrict__ f1bb,
                  const float* __restrict__ f2w, const float* __restrict__ f2b,
                  const float* __restrict__ f2g, const float* __restrict__ f2bb,
                  const float* __restrict__ clw, const float* __restrict__ clb,
                  float* __restrict__ outp, int t)
{
    const int b = blockIdx.x, tid = threadIdx.x;
    const int wave = tid >> 6, lane = tid & 63;
    __shared__ float red[8];
    __shared__ float dred[4][32];
    __shared__ float fin[32];
    __shared__ float kr[16], ki[16];
    __shared__ float zs[768];
    __shared__ float h1s[256];
    __shared__ float h2s[128];

    const float sa = sa_p[0];
    float v[3], zo[3];
    float s = 0.f, s2 = 0.f;
#pragma unroll
    for (int j = 0; j < 3; ++j) {
        int c = tid + 256 * j;
        zo[j] = z[(size_t)b * Dv + c];
        float val = zo[j] + sa * za[(size_t)b * Dv + c];
        v[j] = val; s += val; s2 += val * val;
    }
#pragma unroll
    for (int dd = 1; dd < 64; dd <<= 1) { s += __shfl_xor(s, dd); s2 += __shfl_xor(s2, dd); }
    if (lane == 0) { red[wave * 2] = s; red[wave * 2 + 1] = s2; }
    __syncthreads();
    {
        const float mean = (red[0] + red[2] + red[4] + red[6]) * (1.f / 768.f);
        const float var  = (red[1] + red[3] + red[5] + red[7]) * (1.f / 768.f) - mean * mean;
        const float rstd = rsqrtf(var + 1e-5f);
#pragma unroll
        for (int j = 0; j < 3; ++j) {
            int c = tid + 256 * j;
            v[j] = (v[j] - mean) * rstd * g1[c] + b1[c];   // v now = z1
        }
    }
    float Fc[16], Fs[16];
#pragma unroll
    for (int k = 0; k < 16; ++k) { Fc[k] = 0.f; Fs[k] = 0.f; }
#pragma unroll
    for (int j = 0; j < 3; ++j) {
        int c = tid + 256 * j;
#pragma unroll
        for (int k = 0; k < 16; ++k) {
            Fc[k] = fmaf(v[j], twc[k * Dv + c], Fc[k]);
            Fs[k] = fmaf(v[j], tws[k * Dv + c], Fs[k]);
        }
    }
#pragma unroll
    for (int dd = 1; dd < 64; dd <<= 1) {
#pragma unroll
        for (int k = 0; k < 16; ++k) { Fc[k] += __shfl_xor(Fc[k], dd); Fs[k] += __shfl_xor(Fs[k], dd); }
    }
    if (lane == 0) {
#pragma unroll
        for (int k = 0; k < 16; ++k) { dred[wave][k] = Fc[k]; dred[wave][16 + k] = Fs[k]; }
    }
    __syncthreads();
    if (tid < 32) fin[tid] = dred[0][tid] + dred[1][tid] + dred[2][tid] + dred[3][tid];
    __syncthreads();
    if (tid < 16) {
        float Sc = fin[tid], Ss = fin[16 + tid];   // fft_k = Sc - i*Ss
        float fr = filt_t[tid * 2], fi = filt_t[tid * 2 + 1];
        kr[tid] = Sc * fr + Ss * fi;
        ki[tid] = Sc * fi - Ss * fr;
    }
    __syncthreads();

    const float sd  = sd_p[0];
    const float gv  = 1.f / (1.f + expf(-gate_p[0]));
    const float bnc = 1.f / sqrtf(1.f + 1e-5f);
    float w3[3];
    s = 0.f; s2 = 0.f;
#pragma unroll
    for (int j = 0; j < 3; ++j) {
        int c = tid + 256 * j;
        float den = pb_t[c];
#pragma unroll
        for (int k = 0; k < 16; ++k) {
            den = fmaf(kr[k], csC_t[k * Dv + c], den);
            den = fmaf(-ki[k], csS_t[k * Dv + c], den);
        }
        float val = v[j] + sd * den;
        w3[j] = val; s += val; s2 += val * val;
    }
#pragma unroll
    for (int dd = 1; dd < 64; dd <<= 1) { s += __shfl_xor(s, dd); s2 += __shfl_xor(s2, dd); }
    if (lane == 0) { red[wave * 2] = s; red[wave * 2 + 1] = s2; }
    __syncthreads();
    const float mean2 = (red[0] + red[2] + red[4] + red[6]) * (1.f / 768.f);
    const float var2  = (red[1] + red[3] + red[5] + red[7]) * (1.f / 768.f) - mean2 * mean2;
    const float rstd2 = rsqrtf(var2 + 1e-5f);
#pragma unroll
    for (int j = 0; j < 3; ++j) {
        int c = tid + 256 * j;
        float z2v = (w3[j] - mean2) * rstd2 * g2[c] + b2[c];
        float z3v = gv * z2v + (1.f - gv) * zo[j];
        float zn  = z3v * (bng[c] * bnc) + bnb[c];
        z[(size_t)b * Dv + c] = zn;
        ushort_t hi, lo; split2(zn, hi, lo);
        zbf[(size_t)b * Dv + c] = hi;
        zbf[(size_t)b * Dv + c + ZL] = lo;
        zs[c] = zn;
    }
    __syncthreads();
    float h = f1b[tid];
    for (int d = 0; d < 768; ++d) h = fmaf(zs[d], f1w[(size_t)d * 256 + tid], h);
    h = h * (f1g[tid] * bnc) + f1bb[tid];
    h1s[tid] = fmaxf(h, 0.f);
    __syncthreads();
    if (tid < 128) {
        float h2 = f2b[tid];
        for (int i2 = 0; i2 < 256; ++i2) h2 = fmaf(h1s[i2], f2w[(size_t)i2 * 128 + tid], h2);
        h2 = h2 * (f2g[tid] * bnc) + f2bb[tid];
        h2s[tid] = fmaxf(h2, 0.f);
    }
    __syncthreads();
    if (tid < NCv) {
        float lg = clb[tid];
        for (int i2 = 0; i2 < 128; ++i2) lg = fmaf(h2s[i2], clw[(size_t)i2 * NCv + tid], lg);
        lg *= 0.25f;
        if (t == 0) outp[(size_t)b * NCv + tid] = lg;
        else        outp[(size_t)b * NCv + tid] += lg;
    }
}

// ---------------------------------------------------------------------------
extern "C" void kernel_launch(void* const* d_in, const int* in_sizes, int n_in,
                              void* d_out, int out_size, void* d_ws, size_t ws_size,
                              hipStream_t stream)
{
    (void)in_sizes; (void)n_in; (void)out_size; (void)ws_size;
    const float* x      = (const float*)d_in[0];
    const float* pool_w = (const float*)d_in[1];
    const float* w_q   = (const float*)d_in[3];
    const float* w_k   = (const float*)d_in[4];
    const float* w_v   = (const float*)d_in[5];
    const float* b_qkv = (const float*)d_in[6];
    const float* w_o   = (const float*)d_in[7];
    const float* b_o   = (const float*)d_in[8];
    const float* ln1_g = (const float*)d_in[9];
    const float* ln1_b = (const float*)d_in[10];
    const float* ln2_g = (const float*)d_in[11];
    const float* ln2_b = (const float*)d_in[12];
    const float* s_re  = (const float*)d_in[13];
    const float* s_im  = (const float*)d_in[14];
    const float* proj_w= (const float*)d_in[15];
    const float* proj_b= (const float*)d_in[16];
    const float* bn_g  = (const float*)d_in[17];
    const float* bn_b  = (const float*)d_in[18];
    const float* gate  = (const float*)d_in[19];
    const float* s_at  = (const float*)d_in[20];
    const float* s_dn  = (const float*)d_in[21];
    const float* f1w   = (const float*)d_in[22];
    const float* f1b   = (const float*)d_in[23];
    const float* f1g   = (const float*)d_in[24];
    const float* f1bb  = (const float*)d_in[25];
    const float* f2w   = (const float*)d_in[26];
    const float* f2b   = (const float*)d_in[27];
    const float* f2g   = (const float*)d_in[28];
    const float* f2bb  = (const float*)d_in[29];
    const float* clw   = (const float*)d_in[30];
    const float* clb   = (const float*)d_in[31];
    float* out = (float*)d_out;

    // ws layout (floats first, then ushort planes)
    float* ws   = (float*)d_ws;
    float* twc  = ws;                       // 12288
    float* tws  = twc + 12288;              // 12288
    float* filt = tws + 12288;              // 128
    float* csC  = filt + 128;               // 49152
    float* csS  = csC + 49152;              // 49152
    float* z    = csS + 49152;              // 196608
    float* za   = z + 196608;               // 196608
    float* Qk   = za + 196608;              // 1572864
    float* pacc = Qk + 1572864;             // 6291456 (max(pool 16*B*D, attn 4*B*H*D))
    float* pmlf = pacc + 6291456;           // 16384
    ushort_t* xbf  = (ushort_t*)(pmlf + 16384);  // 100663296
    ushort_t* zbf  = xbf + 100663296;       // 2*196608 (hi,lo)
    ushort_t* qbf  = zbf + 2 * ZL;          // 2*196608
    ushort_t* xwbf = qbf + 2 * ZL;          // 2*1572864
    ushort_t* obf  = xwbf + 2 * XWL;        // 2*196608
    ushort_t* wspl = obf + 2 * ZL;          // 3 * 2*WL (wq,wv,wo hi/lo)
    ushort_t* wkT  = wspl + 6 * WL;         // 2*WL
    float2* pml = (float2*)pmlf;
    ushort_t* wqbf = wspl;
    ushort_t* wvbf = wspl + 2 * WL;
    ushort_t* wobf = wspl + 4 * WL;

    pre1_kernel<<<112, 256, 0, stream>>>(twc, tws, s_re, s_im, filt);
    cs_kernel<<<768, 256, 0, stream>>>(proj_w, twc, tws, csC, csS);
    cvt3_kernel<<<3456, 256, 0, stream>>>(w_q, w_v, w_o, wspl);
    wkT_kernel<<<dim3(12, 32), 256, 0, stream>>>(w_k, wkT);

    pool_cvt_kernel<<<dim3(256, 2), 512, 0, stream>>>(x, pool_w, xbf, pacc, pml);
    merge_kernel<1, 16, true><<<256, 256, 0, stream>>>(pacc, pml, zbf, ZL, z);

    const float iscale = (float)(1.0 / sqrt(96.0));
    for (int t = 0; t < 4; ++t) {
        // q = z @ w_q[t]^T + bq  -> split bf16
        mgemm_kernel<0, true><<<dim3(12, 4), 256, 0, stream>>>(
            zbf, ZL, wqbf + (size_t)t * WT, WL, b_qkv + (size_t)t * 2304, qbf, ZL);
        // Qk[b,h,:] = q_h @ wkT[t,h] -> f32
        mgemm_kernel<1, false><<<dim3(12, 4, 8), 256, 0, stream>>>(
            qbf, ZL, wkT + (size_t)t * WT, WL, nullptr, Qk, 0);
        // attention stream over bf16 x (no-LDS, wave = slice x head-pair)
        attn_flash_kernel<<<dim3(256, 2), 512, 0, stream>>>(xbf, Qk, pacc, pml, iscale);
        merge_kernel<8, 4, false><<<256, 256, 0, stream>>>(pacc, pml, xwbf, XWL, nullptr);
        // o = W_v[t] xw(head) + bv -> split bf16
        mgemm_kernel<2, true><<<dim3(8, 4), 256, 0, stream>>>(
            xwbf, XWL, wvbf + (size_t)t * WT, WL, b_qkv + (size_t)t * 2304 + 1536, obf, ZL);
        // za = o @ w_o[t]^T + bo -> f32
        mgemm_kernel<0, false><<<dim3(12, 4), 256, 0, stream>>>(
            obf, ZL, wobf + (size_t)t * WT, WL, b_o + (size_t)t * Dv, za, 0);
        // fused LN1/DFT/denoise/LN2/gate/BN/classify
        lnden_kernel<<<256, 256, 0, stream>>>(
            z, zbf, za,
            ln1_g + (size_t)t * Dv, ln1_b + (size_t)t * Dv,
            ln2_g + (size_t)t * Dv, ln2_b + (size_t)t * Dv,
            bn_g + (size_t)t * Dv, bn_b + (size_t)t * Dv,
            gate + t, s_at + t, s_dn + t,
            twc, tws, filt + (size_t)t * 32,
            csC + (size_t)t * 12288, csS + (size_t)t * 12288,
            proj_b + (size_t)t * Dv,
            f1w, f1b, f1g, f1bb, f2w, f2b, f2g, f2bb,
            clw, clb, out, t);
    }
}